// Round 11
// baseline (236.180 us; speedup 1.0000x reference)
//
#include <hip/hip_runtime.h>
#include <stdint.h>

typedef __bf16 bf16x8 __attribute__((ext_vector_type(8)));
typedef float f32x4 __attribute__((ext_vector_type(4)));

using gvoid = const __attribute__((address_space(1))) void;
using lvoid = __attribute__((address_space(3))) void;

__device__ __forceinline__ unsigned short f2bf(float f) {
    union { float f; unsigned u; } x; x.f = f;
    unsigned u = x.u;
    u += 0x7FFFu + ((u >> 16) & 1u);   // round-to-nearest-even
    return (unsigned short)(u >> 16);
}
__device__ __forceinline__ unsigned pack2(float lo, float hi) {
    return ((unsigned)f2bf(hi) << 16) | (unsigned)f2bf(lo);
}

// -------- fused: A fp32->bf16 streaming convert  +  layer-1 small GEMM --------
// blocks [0, 2048): convert; blocks [2048, 2304): Yt1 = (nf @ W1 + b1)^T.
__global__ __launch_bounds__(256)
void convert_small(const float* __restrict__ Amat, unsigned short* __restrict__ Abf,
                   const float* __restrict__ X, const float* __restrict__ W,
                   const float* __restrict__ b, unsigned short* __restrict__ Yt) {
    __shared__ float Xs[32 * 129];
    __shared__ float Ws[128 * 64];
    __shared__ float bs[64];
    const int t = threadIdx.x;

    if (blockIdx.x < 2048) {
        const int n8 = 8192 * 8192 / 8;
        int idx = blockIdx.x * 256 + t;
        const float4* in4 = (const float4*)Amat;
        uint4* out8 = (uint4*)Abf;
        for (int i = idx; i < n8; i += 2048 * 256) {
            float4 a = in4[2 * i], c = in4[2 * i + 1];
            uint4 o;
            o.x = pack2(a.x, a.y);
            o.y = pack2(a.z, a.w);
            o.z = pack2(c.x, c.y);
            o.w = pack2(c.z, c.w);
            out8[i] = o;
        }
        return;
    }

    const int i0 = (blockIdx.x - 2048) * 32;
    for (int e = t; e < 32 * 128; e += 256) {
        int r = e >> 7, c = e & 127;
        Xs[r * 129 + c] = X[(size_t)(i0 + r) * 128 + c];
    }
    for (int e = t; e < 128 * 64; e += 256) Ws[e] = W[e];
    if (t < 64) bs[t] = b[t];
    __syncthreads();

    const int i = t & 31;
    const int jg = t >> 5;
    float acc[8];
#pragma unroll
    for (int jj = 0; jj < 8; ++jj) acc[jj] = 0.0f;
    for (int k = 0; k < 128; ++k) {
        float xv = Xs[i * 129 + k];
        const float4* wr = (const float4*)&Ws[k * 64 + jg * 8];
        float4 w0 = wr[0], w1 = wr[1];
        acc[0] += xv * w0.x; acc[1] += xv * w0.y;
        acc[2] += xv * w0.z; acc[3] += xv * w0.w;
        acc[4] += xv * w1.x; acc[5] += xv * w1.y;
        acc[6] += xv * w1.z; acc[7] += xv * w1.w;
    }
#pragma unroll
    for (int jj = 0; jj < 8; ++jj) {
        int j = jg * 8 + jj;
        Yt[(size_t)j * 8192 + i0 + i] = f2bf(acc[jj] + bs[j]);
    }
}

// ---------------- big GEMM: P[ks] = Abf[rows,kslice] @ Y[kslice,64] ----------------
// BM=64, BN=64, BK=64, 4 waves (2M x 2N), split-K = 8 -> grid 128x8 = 1024 blocks
// (4/CU). R5 skeleton (stage -> counted-vmcnt + barrier -> compute -> barrier),
// but B now lives in REGISTERS (double-buffered, loaded 1 tile ahead via plain
// global loads; L2-resident Yt) — only A goes through LDS (XOR-swizzled
// source, linear global_load_lds dest). LDS 16 KB, vmcnt(6) = 2 A-gloads +
// 4 B-loads of the next tile stay in flight across the barrier.
__global__ __launch_bounds__(256, 4)
void big_gemm(const unsigned short* __restrict__ Ab,
              const unsigned short* __restrict__ Yt,
              float* __restrict__ P) {
    __shared__ unsigned short As[2][64 * 64];  // 2 x 8 KB, A only
    const int t = threadIdx.x;
    const int lane = t & 63, wid = t >> 6;
    const int lane15 = lane & 15, lane4 = lane >> 4;
    const int wm = wid >> 1, wn = wid & 1;
    const int row0 = blockIdx.x * 64;
    const int kbase = blockIdx.y * 1024;   // split-K = 8

    const unsigned short* bP[2][2];
#pragma unroll
    for (int n = 0; n < 2; ++n)
#pragma unroll
        for (int ks = 0; ks < 2; ++ks)
            bP[n][ks] = Yt + (size_t)(wn * 32 + n * 16 + lane15) * 8192 +
                        kbase + ks * 32 + lane4 * 8;

    f32x4 acc[2][2];
    const f32x4 z4 = {0.f, 0.f, 0.f, 0.f};
#pragma unroll
    for (int m = 0; m < 2; ++m)
#pragma unroll
        for (int n = 0; n < 2; ++n) acc[m][n] = z4;

    bf16x8 breg[2][2][2];   // [buf][n][ks], all indices compile-time (full unroll)

    auto stageA = [&](int slot, int kt) {
#pragma unroll
        for (int ii = 0; ii < 2; ++ii) {
            int p = ii * 256 + wid * 64 + lane;
            int r = p >> 3;
            int c = (p & 7) ^ (r & 7);  // inverse swizzle on source, linear dest
            const unsigned short* gp = Ab + (size_t)(row0 + r) * 8192 + (kt + c * 8);
            unsigned short* lp = &As[slot][(ii * 256 + wid * 64) * 8];
            __builtin_amdgcn_global_load_lds((gvoid*)gp, (lvoid*)lp, 16, 0, 0);
        }
    };

    stageA(0, kbase);
#pragma unroll
    for (int n = 0; n < 2; ++n)
#pragma unroll
        for (int ks = 0; ks < 2; ++ks)
            breg[0][n][ks] = *(const bf16x8*)(bP[n][ks]);

#pragma unroll
    for (int tt = 0; tt < 16; ++tt) {
        if (tt + 1 < 16) {
            stageA((tt + 1) & 1, kbase + (tt + 1) * 64);
#pragma unroll
            for (int n = 0; n < 2; ++n)
#pragma unroll
                for (int ks = 0; ks < 2; ++ks)
                    breg[(tt + 1) & 1][n][ks] =
                        *(const bf16x8*)(bP[n][ks] + (tt + 1) * 64);
            // next tile's 6 vm-ops (2 A-glds + 4 B-loads) stay in flight
            asm volatile("s_waitcnt vmcnt(6)\n\ts_barrier" ::: "memory");
        } else {
            asm volatile("s_waitcnt vmcnt(0)\n\ts_barrier" ::: "memory");
        }
#pragma unroll
        for (int ks = 0; ks < 2; ++ks) {
            bf16x8 af[2];
#pragma unroll
            for (int m = 0; m < 2; ++m) {
                int r = wm * 32 + m * 16 + lane15;
                int c = ks * 4 + lane4;
                af[m] = *(const bf16x8*)&As[tt & 1][((r << 3) | (c ^ (r & 7))) << 3];
            }
#pragma unroll
            for (int m = 0; m < 2; ++m)
#pragma unroll
                for (int n = 0; n < 2; ++n)
                    acc[m][n] = __builtin_amdgcn_mfma_f32_16x16x32_bf16(
                        af[m], breg[tt & 1][n][ks], acc[m][n], 0, 0, 0);
        }
        // trailing barrier: protects As[(tt+1)&1] from next iter's stageA
        asm volatile("s_barrier" ::: "memory");
    }

    // C/D layout: col = lane&15, row = (lane>>4)*4 + q
    float* Po = P + (size_t)blockIdx.y * (8192 * 64);
#pragma unroll
    for (int m = 0; m < 2; ++m) {
        int r = row0 + wm * 32 + m * 16 + lane4 * 4;
#pragma unroll
        for (int n = 0; n < 2; ++n) {
            int cc = wn * 32 + n * 16 + lane15;
#pragma unroll
            for (int q = 0; q < 4; ++q)
                Po[(size_t)(r + q) * 64 + cc] = acc[m][n][q];
        }
    }
}

// ---------------- fused: reduce split-K(8) + poly + next layer's small GEMM --------
// MODE 0: X1 = poly(z); store X1; Yt = (X1 Wn + bn)^T
// MODE 1: v = X1 + poly(z); Yt = (v Wn + bn)^T     (X2 never materialized)
template <int MODE>
__global__ __launch_bounds__(256) void fused_reduce(const float* __restrict__ P,
                                                    const float* __restrict__ cf,
                                                    const float* __restrict__ Wn,
                                                    const float* __restrict__ bn,
                                                    int cout,
                                                    float* __restrict__ X1,
                                                    unsigned short* __restrict__ Yt) {
    __shared__ float Xs[64 * 33];   // [j][i]
    __shared__ float Ws[64 * 64];
    __shared__ float bs[64];
    const int t = threadIdx.x;
    const int i0 = blockIdx.x * 32;
    const int NT4 = 8192 * 64 / 4;
    const float4* P4 = (const float4*)P;
    float4* X14 = (float4*)X1;

    for (int e = t; e < 64 * 64; e += 256) {
        int k = e >> 6, j = e & 63;
        Ws[e] = (j < cout) ? Wn[k * cout + j] : 0.0f;
    }
    if (t < 64) bs[t] = (t < cout) ? bn[t] : 0.0f;
    const float c0 = cf[0], c1 = cf[1], c2 = cf[2];

#pragma unroll
    for (int s = 0; s < 2; ++s) {
        int e4 = s * 256 + t;          // 512 float4 = 32 rows x 16
        int i = e4 >> 4, jc = e4 & 15;
        int base4 = (i0 + i) * 16 + jc;
        float4 z = {0.f, 0.f, 0.f, 0.f};
#pragma unroll
        for (int ks = 0; ks < 8; ++ks) {
            float4 p = P4[(size_t)ks * NT4 + base4];
            z.x += p.x; z.y += p.y; z.z += p.z; z.w += p.w;
        }
        float4 v;
        v.x = z.x * (c0 + z.x * (c1 + z.x * c2));
        v.y = z.y * (c0 + z.y * (c1 + z.y * c2));
        v.z = z.z * (c0 + z.z * (c1 + z.z * c2));
        v.w = z.w * (c0 + z.w * (c1 + z.w * c2));
        if (MODE == 0) {
            X14[base4] = v;
        } else {
            float4 xr = X14[base4];
            v.x += xr.x; v.y += xr.y; v.z += xr.z; v.w += xr.w;
        }
        Xs[(jc * 4 + 0) * 33 + i] = v.x;
        Xs[(jc * 4 + 1) * 33 + i] = v.y;
        Xs[(jc * 4 + 2) * 33 + i] = v.z;
        Xs[(jc * 4 + 3) * 33 + i] = v.w;
    }
    __syncthreads();

    const int i = t & 31;
    const int jg = t >> 5;
    float acc[8];
#pragma unroll
    for (int jj = 0; jj < 8; ++jj) acc[jj] = 0.0f;
    for (int k = 0; k < 64; ++k) {
        float xv = Xs[k * 33 + i];
        const float4* wr = (const float4*)&Ws[k * 64 + jg * 8];
        float4 w0 = wr[0], w1 = wr[1];
        acc[0] += xv * w0.x; acc[1] += xv * w0.y;
        acc[2] += xv * w0.z; acc[3] += xv * w0.w;
        acc[4] += xv * w1.x; acc[5] += xv * w1.y;
        acc[6] += xv * w1.z; acc[7] += xv * w1.w;
    }
#pragma unroll
    for (int jj = 0; jj < 8; ++jj) {
        int j = jg * 8 + jj;
        Yt[(size_t)j * 8192 + i0 + i] = f2bf(acc[jj] + bs[j]);
    }
}

// ---------------- final: reduce(8) + poly -> out [8192 x 40], float4 ----------------
__global__ void reduce_out(const float* __restrict__ P, const float* __restrict__ cf,
                           float* __restrict__ out) {
    int e4 = blockIdx.x * 256 + threadIdx.x;   // < 131072
    const int NT4 = 8192 * 64 / 4;
    const float4* P4 = (const float4*)P;
    float4 z = {0.f, 0.f, 0.f, 0.f};
#pragma unroll
    for (int ks = 0; ks < 8; ++ks) {
        float4 p = P4[(size_t)ks * NT4 + e4];
        z.x += p.x; z.y += p.y; z.z += p.z; z.w += p.w;
    }
    float c0 = cf[0], c1 = cf[1], c2 = cf[2];
    float4 v;
    v.x = z.x * (c0 + z.x * (c1 + z.x * c2));
    v.y = z.y * (c0 + z.y * (c1 + z.y * c2));
    v.z = z.z * (c0 + z.z * (c1 + z.z * c2));
    v.w = z.w * (c0 + z.w * (c1 + z.w * c2));
    int i = e4 >> 4, jc = e4 & 15;
    if (jc < 10) ((float4*)out)[i * 10 + jc] = v;   // 40 cols = 10 float4
}

extern "C" void kernel_launch(void* const* d_in, const int* in_sizes, int n_in,
                              void* d_out, int out_size, void* d_ws, size_t ws_size,
                              hipStream_t stream) {
    const float* nf   = (const float*)d_in[0];
    const float* Amat = (const float*)d_in[1];
    const float* W1   = (const float*)d_in[2];
    const float* b1   = (const float*)d_in[3];
    const float* c1   = (const float*)d_in[4];
    const float* W2   = (const float*)d_in[5];
    const float* b2   = (const float*)d_in[6];
    const float* c2   = (const float*)d_in[7];
    const float* W3   = (const float*)d_in[8];
    const float* b3   = (const float*)d_in[9];
    const float* c3   = (const float*)d_in[10];
    float* out = (float*)d_out;

    char* ws = (char*)d_ws;
    unsigned short* Abf = (unsigned short*)(ws);                 // 134217728 B
    unsigned short* Yt  = (unsigned short*)(ws + 134217728);     //   1048576 B
    float* X1           = (float*)(ws + 135266304);              //   2097152 B
    float* Pp           = (float*)(ws + 137363456);              //  16777216 B
    // total: 154140672 B

    // fused: streaming conversion + layer-1 feature transform
    convert_small<<<2304, 256, 0, stream>>>(Amat, Abf, nf, W1, b1, Yt);

    // layer 1
    big_gemm<<<dim3(128, 8), 256, 0, stream>>>(Abf, Yt, Pp);
    fused_reduce<0><<<256, 256, 0, stream>>>(Pp, c1, W2, b2, 64, X1, Yt);

    // layer 2 (residual folded into fused_reduce<1>)
    big_gemm<<<dim3(128, 8), 256, 0, stream>>>(Abf, Yt, Pp);
    fused_reduce<1><<<256, 256, 0, stream>>>(Pp, c2, W3, b3, 40, X1, Yt);

    // layer 3
    big_gemm<<<dim3(128, 8), 256, 0, stream>>>(Abf, Yt, Pp);
    reduce_out<<<512, 256, 0, stream>>>(Pp, c3, out);
}

// Round 12
// 216.467 us; speedup vs baseline: 1.0911x; 1.0911x over previous
//
#include <hip/hip_runtime.h>
#include <stdint.h>

typedef __bf16 bf16x8 __attribute__((ext_vector_type(8)));
typedef float f32x4 __attribute__((ext_vector_type(4)));

using gvoid = const __attribute__((address_space(1))) void;
using lvoid = __attribute__((address_space(3))) void;

__device__ __forceinline__ unsigned short f2bf(float f) {
    union { float f; unsigned u; } x; x.f = f;
    unsigned u = x.u;
    u += 0x7FFFu + ((u >> 16) & 1u);   // round-to-nearest-even
    return (unsigned short)(u >> 16);
}
__device__ __forceinline__ unsigned pack2(float lo, float hi) {
    return ((unsigned)f2bf(hi) << 16) | (unsigned)f2bf(lo);
}

// -------- fused: A fp32->bf16 streaming convert  +  layer-1 small GEMM --------
// blocks [0, 2048): convert; blocks [2048, 2304): Yt1 = (nf @ W1 + b1)^T.
__global__ __launch_bounds__(256)
void convert_small(const float* __restrict__ Amat, unsigned short* __restrict__ Abf,
                   const float* __restrict__ X, const float* __restrict__ W,
                   const float* __restrict__ b, unsigned short* __restrict__ Yt) {
    __shared__ float Xs[32 * 129];
    __shared__ float Ws[128 * 64];
    __shared__ float bs[64];
    const int t = threadIdx.x;

    if (blockIdx.x < 2048) {
        const int n8 = 8192 * 8192 / 8;
        int idx = blockIdx.x * 256 + t;
        const float4* in4 = (const float4*)Amat;
        uint4* out8 = (uint4*)Abf;
        for (int i = idx; i < n8; i += 2048 * 256) {
            float4 a = in4[2 * i], c = in4[2 * i + 1];
            uint4 o;
            o.x = pack2(a.x, a.y);
            o.y = pack2(a.z, a.w);
            o.z = pack2(c.x, c.y);
            o.w = pack2(c.z, c.w);
            out8[i] = o;
        }
        return;
    }

    const int i0 = (blockIdx.x - 2048) * 32;
    for (int e = t; e < 32 * 128; e += 256) {
        int r = e >> 7, c = e & 127;
        Xs[r * 129 + c] = X[(size_t)(i0 + r) * 128 + c];
    }
    for (int e = t; e < 128 * 64; e += 256) Ws[e] = W[e];
    if (t < 64) bs[t] = b[t];
    __syncthreads();

    const int i = t & 31;
    const int jg = t >> 5;
    float acc[8];
#pragma unroll
    for (int jj = 0; jj < 8; ++jj) acc[jj] = 0.0f;
    for (int k = 0; k < 128; ++k) {
        float xv = Xs[i * 129 + k];
        const float4* wr = (const float4*)&Ws[k * 64 + jg * 8];
        float4 w0 = wr[0], w1 = wr[1];
        acc[0] += xv * w0.x; acc[1] += xv * w0.y;
        acc[2] += xv * w0.z; acc[3] += xv * w0.w;
        acc[4] += xv * w1.x; acc[5] += xv * w1.y;
        acc[6] += xv * w1.z; acc[7] += xv * w1.w;
    }
#pragma unroll
    for (int jj = 0; jj < 8; ++jj) {
        int j = jg * 8 + jj;
        Yt[(size_t)j * 8192 + i0 + i] = f2bf(acc[jj] + bs[j]);
    }
}

// ---------------- big GEMM: P[ks] = Abf[rows,kslice] @ Y[kslice,64] ----------------
// 2-WAVE blocks (128 threads), BM=32, BN=64, BK=64, split-K = 8 -> grid 256x8 =
// 2048 blocks, 6 blocks/CU (24 KB LDS). EXACT R5 skeleton otherwise:
//   stage(t+1) -> s_waitcnt vmcnt(6) -> s_barrier -> compute(t) -> s_barrier
// Per wave per tile: 6 staging ops (2 A gload_lds + 4 B gload_lds), 8 ds_read_b128,
// 8 MFMA — identical per-wave ratios to R5; only the lock-step width (2 waves vs 4)
// and blocks/CU (6 vs 4) change. XOR swizzle source-side, linear LDS dest.
__global__ __launch_bounds__(128, 3)
void big_gemm(const unsigned short* __restrict__ Ab,
              const unsigned short* __restrict__ Yt,
              float* __restrict__ P) {
    __shared__ unsigned short As[2][32 * 64];  // 2 x 4 KB
    __shared__ unsigned short Bs[2][64 * 64];  // 2 x 8 KB
    const int t = threadIdx.x;           // 0..127
    const int lane = t & 63, wid = t >> 6;  // wid = wn in {0,1}
    const int lane15 = lane & 15, lane4 = lane >> 4;
    const int row0 = blockIdx.x * 32;
    const int kbase = blockIdx.y * 1024;   // split-K = 8

    f32x4 acc[2][2];
    const f32x4 z4 = {0.f, 0.f, 0.f, 0.f};
#pragma unroll
    for (int m = 0; m < 2; ++m)
#pragma unroll
        for (int n = 0; n < 2; ++n) acc[m][n] = z4;

    auto stage = [&](int slot, int kt) {
        // A tile: 32 rows x 64 k = 256 x 16B chunks -> 2 rounds x 128 threads
#pragma unroll
        for (int ii = 0; ii < 2; ++ii) {
            int p = ii * 128 + t;
            int r = p >> 3;
            int c = (p & 7) ^ (r & 7);  // inverse swizzle on source, linear dest
            const unsigned short* gp = Ab + (size_t)(row0 + r) * 8192 + (kt + c * 8);
            unsigned short* lp = &As[slot][(ii * 128 + wid * 64) * 8];
            __builtin_amdgcn_global_load_lds((gvoid*)gp, (lvoid*)lp, 16, 0, 0);
        }
        // B tile: 64 n x 64 k = 512 chunks -> 4 rounds
#pragma unroll
        for (int ii = 0; ii < 4; ++ii) {
            int q = ii * 128 + t;
            int n = q >> 3;
            int c = (q & 7) ^ (n & 7);
            const unsigned short* gp = Yt + (size_t)n * 8192 + (kt + c * 8);
            unsigned short* lp = &Bs[slot][(ii * 128 + wid * 64) * 8];
            __builtin_amdgcn_global_load_lds((gvoid*)gp, (lvoid*)lp, 16, 0, 0);
        }
    };

    stage(0, kbase);
    const int NIT = 16;  // 1024 / 64
    for (int tt = 0; tt < NIT; ++tt) {
        if (tt + 1 < NIT) {
            stage((tt + 1) & 1, kbase + (tt + 1) * 64);
            // tile t's 6 staging ops done; tile t+1's 6 stay in flight
            asm volatile("s_waitcnt vmcnt(6)\n\ts_barrier" ::: "memory");
        } else {
            asm volatile("s_waitcnt vmcnt(0)\n\ts_barrier" ::: "memory");
        }
#pragma unroll
        for (int ks = 0; ks < 2; ++ks) {
            bf16x8 af[2], bfr[2];
#pragma unroll
            for (int m = 0; m < 2; ++m) {
                int r = m * 16 + lane15;
                int c = ks * 4 + lane4;
                af[m] = *(const bf16x8*)&As[tt & 1][((r << 3) | (c ^ (r & 7))) << 3];
            }
#pragma unroll
            for (int n = 0; n < 2; ++n) {
                int rn = wid * 32 + n * 16 + lane15;
                int c = ks * 4 + lane4;
                bfr[n] = *(const bf16x8*)&Bs[tt & 1][((rn << 3) | (c ^ (rn & 7))) << 3];
            }
#pragma unroll
            for (int m = 0; m < 2; ++m)
#pragma unroll
                for (int n = 0; n < 2; ++n)
                    acc[m][n] = __builtin_amdgcn_mfma_f32_16x16x32_bf16(
                        af[m], bfr[n], acc[m][n], 0, 0, 0);
        }
        // trailing barrier: protect buffer (tt+1)&1 from next iteration's stage
        asm volatile("s_barrier" ::: "memory");
    }

    // C/D layout: col = lane&15, row = (lane>>4)*4 + q
    float* Po = P + (size_t)blockIdx.y * (8192 * 64);
#pragma unroll
    for (int m = 0; m < 2; ++m) {
        int r = row0 + m * 16 + lane4 * 4;
#pragma unroll
        for (int n = 0; n < 2; ++n) {
            int cc = wid * 32 + n * 16 + lane15;
#pragma unroll
            for (int q = 0; q < 4; ++q)
                Po[(size_t)(r + q) * 64 + cc] = acc[m][n][q];
        }
    }
}

// ---------------- fused: reduce split-K(8) + poly + next layer's small GEMM --------
// MODE 0: X1 = poly(z); store X1; Yt = (X1 Wn + bn)^T
// MODE 1: v = X1 + poly(z); Yt = (v Wn + bn)^T     (X2 never materialized)
template <int MODE>
__global__ __launch_bounds__(256) void fused_reduce(const float* __restrict__ P,
                                                    const float* __restrict__ cf,
                                                    const float* __restrict__ Wn,
                                                    const float* __restrict__ bn,
                                                    int cout,
                                                    float* __restrict__ X1,
                                                    unsigned short* __restrict__ Yt) {
    __shared__ float Xs[64 * 33];   // [j][i]
    __shared__ float Ws[64 * 64];
    __shared__ float bs[64];
    const int t = threadIdx.x;
    const int i0 = blockIdx.x * 32;
    const int NT4 = 8192 * 64 / 4;
    const float4* P4 = (const float4*)P;
    float4* X14 = (float4*)X1;

    for (int e = t; e < 64 * 64; e += 256) {
        int k = e >> 6, j = e & 63;
        Ws[e] = (j < cout) ? Wn[k * cout + j] : 0.0f;
    }
    if (t < 64) bs[t] = (t < cout) ? bn[t] : 0.0f;
    const float c0 = cf[0], c1 = cf[1], c2 = cf[2];

#pragma unroll
    for (int s = 0; s < 2; ++s) {
        int e4 = s * 256 + t;          // 512 float4 = 32 rows x 16
        int i = e4 >> 4, jc = e4 & 15;
        int base4 = (i0 + i) * 16 + jc;
        float4 z = {0.f, 0.f, 0.f, 0.f};
#pragma unroll
        for (int ks = 0; ks < 8; ++ks) {
            float4 p = P4[(size_t)ks * NT4 + base4];
            z.x += p.x; z.y += p.y; z.z += p.z; z.w += p.w;
        }
        float4 v;
        v.x = z.x * (c0 + z.x * (c1 + z.x * c2));
        v.y = z.y * (c0 + z.y * (c1 + z.y * c2));
        v.z = z.z * (c0 + z.z * (c1 + z.z * c2));
        v.w = z.w * (c0 + z.w * (c1 + z.w * c2));
        if (MODE == 0) {
            X14[base4] = v;
        } else {
            float4 xr = X14[base4];
            v.x += xr.x; v.y += xr.y; v.z += xr.z; v.w += xr.w;
        }
        Xs[(jc * 4 + 0) * 33 + i] = v.x;
        Xs[(jc * 4 + 1) * 33 + i] = v.y;
        Xs[(jc * 4 + 2) * 33 + i] = v.z;
        Xs[(jc * 4 + 3) * 33 + i] = v.w;
    }
    __syncthreads();

    const int i = t & 31;
    const int jg = t >> 5;
    float acc[8];
#pragma unroll
    for (int jj = 0; jj < 8; ++jj) acc[jj] = 0.0f;
    for (int k = 0; k < 64; ++k) {
        float xv = Xs[k * 33 + i];
        const float4* wr = (const float4*)&Ws[k * 64 + jg * 8];
        float4 w0 = wr[0], w1 = wr[1];
        acc[0] += xv * w0.x; acc[1] += xv * w0.y;
        acc[2] += xv * w0.z; acc[3] += xv * w0.w;
        acc[4] += xv * w1.x; acc[5] += xv * w1.y;
        acc[6] += xv * w1.z; acc[7] += xv * w1.w;
    }
#pragma unroll
    for (int jj = 0; jj < 8; ++jj) {
        int j = jg * 8 + jj;
        Yt[(size_t)j * 8192 + i0 + i] = f2bf(acc[jj] + bs[j]);
    }
}

// ---------------- final: reduce(8) + poly -> out [8192 x 40], float4 ----------------
__global__ void reduce_out(const float* __restrict__ P, const float* __restrict__ cf,
                           float* __restrict__ out) {
    int e4 = blockIdx.x * 256 + threadIdx.x;   // < 131072
    const int NT4 = 8192 * 64 / 4;
    const float4* P4 = (const float4*)P;
    float4 z = {0.f, 0.f, 0.f, 0.f};
#pragma unroll
    for (int ks = 0; ks < 8; ++ks) {
        float4 p = P4[(size_t)ks * NT4 + e4];
        z.x += p.x; z.y += p.y; z.z += p.z; z.w += p.w;
    }
    float c0 = cf[0], c1 = cf[1], c2 = cf[2];
    float4 v;
    v.x = z.x * (c0 + z.x * (c1 + z.x * c2));
    v.y = z.y * (c0 + z.y * (c1 + z.y * c2));
    v.z = z.z * (c0 + z.z * (c1 + z.z * c2));
    v.w = z.w * (c0 + z.w * (c1 + z.w * c2));
    int i = e4 >> 4, jc = e4 & 15;
    if (jc < 10) ((float4*)out)[i * 10 + jc] = v;   // 40 cols = 10 float4
}

extern "C" void kernel_launch(void* const* d_in, const int* in_sizes, int n_in,
                              void* d_out, int out_size, void* d_ws, size_t ws_size,
                              hipStream_t stream) {
    const float* nf   = (const float*)d_in[0];
    const float* Amat = (const float*)d_in[1];
    const float* W1   = (const float*)d_in[2];
    const float* b1   = (const float*)d_in[3];
    const float* c1   = (const float*)d_in[4];
    const float* W2   = (const float*)d_in[5];
    const float* b2   = (const float*)d_in[6];
    const float* c2   = (const float*)d_in[7];
    const float* W3   = (const float*)d_in[8];
    const float* b3   = (const float*)d_in[9];
    const float* c3   = (const float*)d_in[10];
    float* out = (float*)d_out;

    char* ws = (char*)d_ws;
    unsigned short* Abf = (unsigned short*)(ws);                 // 134217728 B
    unsigned short* Yt  = (unsigned short*)(ws + 134217728);     //   1048576 B
    float* X1           = (float*)(ws + 135266304);              //   2097152 B
    float* Pp           = (float*)(ws + 137363456);              //  16777216 B
    // total: 154140672 B

    // fused: streaming conversion + layer-1 feature transform
    convert_small<<<2304, 256, 0, stream>>>(Amat, Abf, nf, W1, b1, Yt);

    // layer 1
    big_gemm<<<dim3(256, 8), 128, 0, stream>>>(Abf, Yt, Pp);
    fused_reduce<0><<<256, 256, 0, stream>>>(Pp, c1, W2, b2, 64, X1, Yt);

    // layer 2 (residual folded into fused_reduce<1>)
    big_gemm<<<dim3(256, 8), 128, 0, stream>>>(Abf, Yt, Pp);
    fused_reduce<1><<<256, 256, 0, stream>>>(Pp, c2, W3, b3, 40, X1, Yt);

    // layer 3
    big_gemm<<<dim3(256, 8), 128, 0, stream>>>(Abf, Yt, Pp);
    reduce_out<<<512, 256, 0, stream>>>(Pp, c3, out);
}

// Round 13
// 214.482 us; speedup vs baseline: 1.1012x; 1.0093x over previous
//
#include <hip/hip_runtime.h>
#include <stdint.h>

typedef __bf16 bf16x8 __attribute__((ext_vector_type(8)));
typedef float f32x4 __attribute__((ext_vector_type(4)));

using gvoid = const __attribute__((address_space(1))) void;
using lvoid = __attribute__((address_space(3))) void;

__device__ __forceinline__ unsigned short f2bf(float f) {
    union { float f; unsigned u; } x; x.f = f;
    unsigned u = x.u;
    u += 0x7FFFu + ((u >> 16) & 1u);   // round-to-nearest-even
    return (unsigned short)(u >> 16);
}
__device__ __forceinline__ unsigned pack2(float lo, float hi) {
    return ((unsigned)f2bf(hi) << 16) | (unsigned)f2bf(lo);
}

// ---------------- Yt = (X @ W + b)^T  as bf16 [64][8192], layer 1 ----------------
template <int CIN>
__global__ __launch_bounds__(256) void small_gemm(const float* __restrict__ X,
                                                  const float* __restrict__ W,
                                                  const float* __restrict__ b,
                                                  int cout,
                                                  unsigned short* __restrict__ Yt) {
    __shared__ float Xs[32 * (CIN + 1)];
    __shared__ float Ws[CIN * 64];
    __shared__ float bs[64];
    const int t = threadIdx.x;
    const int i0 = blockIdx.x * 32;

    for (int e = t; e < 32 * CIN; e += 256) {
        int r = e / CIN, c = e % CIN;
        Xs[r * (CIN + 1) + c] = X[(size_t)(i0 + r) * CIN + c];
    }
    for (int e = t; e < CIN * 64; e += 256) {
        int k = e >> 6, j = e & 63;
        Ws[e] = (j < cout) ? W[k * cout + j] : 0.0f;
    }
    if (t < 64) bs[t] = (t < cout) ? b[t] : 0.0f;
    __syncthreads();

    const int i = t & 31;
    const int jg = t >> 5;
    float acc[8];
#pragma unroll
    for (int jj = 0; jj < 8; ++jj) acc[jj] = 0.0f;

    for (int k = 0; k < CIN; ++k) {
        float xv = Xs[i * (CIN + 1) + k];
        const float4* wr = (const float4*)&Ws[k * 64 + jg * 8];
        float4 w0 = wr[0], w1 = wr[1];
        acc[0] += xv * w0.x; acc[1] += xv * w0.y;
        acc[2] += xv * w0.z; acc[3] += xv * w0.w;
        acc[4] += xv * w1.x; acc[5] += xv * w1.y;
        acc[6] += xv * w1.z; acc[7] += xv * w1.w;
    }
#pragma unroll
    for (int jj = 0; jj < 8; ++jj) {
        int j = jg * 8 + jj;
        Yt[(size_t)j * 8192 + i0 + i] = f2bf(acc[jj] + bs[j]);
    }
}

// ------------- layer-1 GEMM with fused A conversion (R5 skeleton) -------------
// BM=64, BN=64, BK=64, 4 waves (2M x 2N), split-K = 8 -> 1024 blocks, 4/CU.
// A: fp32 reg-load (4 dwordx4/thr) -> cvt -> swizzled ds_write + linear
// global_store of Abf (bf16 master for layers 2/3). B: global_load_lds (R5).
// In-order vmcnt FIFO per iter: [st(t):2][Aregs(t+1):4][Bglds(t+1):2]
//   head wait  vmcnt(8): retires tile-t's B-stage (stores had 1 full iter);
//   post-compute vmcnt(2): retires A-regs (cvt inputs);
//   lgkmcnt(0) publishes ds_writes before the trailing barrier.
// Never waits on freshly-issued stores -> no store-retire in critical path.
__global__ __launch_bounds__(256, 4)
void gemm_conv(const float* __restrict__ Afp,
               unsigned short* __restrict__ Ab,
               const unsigned short* __restrict__ Yt,
               float* __restrict__ P) {
    __shared__ unsigned short As[2][64 * 64];  // 2 x 8 KB
    __shared__ unsigned short Bs[2][64 * 64];  // 2 x 8 KB
    const int t = threadIdx.x;
    const int lane = t & 63, wid = t >> 6;
    const int lane15 = lane & 15, lane4 = lane >> 4;
    const int wm = wid >> 1, wn = wid & 1;
    const int row0 = blockIdx.x * 64;
    const int kbase = blockIdx.y * 1024;   // split-K = 8

    f32x4 acc[2][2];
    const f32x4 z4 = {0.f, 0.f, 0.f, 0.f};
#pragma unroll
    for (int m = 0; m < 2; ++m)
#pragma unroll
        for (int n = 0; n < 2; ++n) acc[m][n] = z4;

    float4 ra[2][2];     // A staging: 2 chunks x 8 fp32 (static indices)
    const int p0 = t, p1 = 256 + t;
    const int r0 = p0 >> 3, c0 = p0 & 7, r1 = p1 >> 3, c1 = p1 & 7;

    auto loadA = [&](int kt) {
        const float* g0 = Afp + (size_t)(row0 + r0) * 8192 + kt + c0 * 8;
        const float* g1 = Afp + (size_t)(row0 + r1) * 8192 + kt + c1 * 8;
        ra[0][0] = *(const float4*)g0; ra[0][1] = *(const float4*)(g0 + 4);
        ra[1][0] = *(const float4*)g1; ra[1][1] = *(const float4*)(g1 + 4);
    };
    auto writeA = [&](int slot, int kt) {
        uint4 ch0, ch1;
        ch0.x = pack2(ra[0][0].x, ra[0][0].y); ch0.y = pack2(ra[0][0].z, ra[0][0].w);
        ch0.z = pack2(ra[0][1].x, ra[0][1].y); ch0.w = pack2(ra[0][1].z, ra[0][1].w);
        ch1.x = pack2(ra[1][0].x, ra[1][0].y); ch1.y = pack2(ra[1][0].z, ra[1][0].w);
        ch1.z = pack2(ra[1][1].x, ra[1][1].y); ch1.w = pack2(ra[1][1].z, ra[1][1].w);
        *(uint4*)&As[slot][((r0 << 3) | (c0 ^ (r0 & 7))) << 3] = ch0;   // swizzled
        *(uint4*)&As[slot][((r1 << 3) | (c1 ^ (r1 & 7))) << 3] = ch1;
        *(uint4*)&Ab[(size_t)(row0 + r0) * 8192 + kt + c0 * 8] = ch0;   // linear
        *(uint4*)&Ab[(size_t)(row0 + r1) * 8192 + kt + c1 * 8] = ch1;
    };
    auto stageB = [&](int slot, int kt) {
#pragma unroll
        for (int ii = 0; ii < 2; ++ii) {
            int q = ii * 256 + wid * 64 + lane;
            int n = q >> 3;
            int c = (q & 7) ^ (n & 7);
            const unsigned short* gp = Yt + (size_t)n * 8192 + (kt + c * 8);
            unsigned short* lp = &Bs[slot][(ii * 256 + wid * 64) * 8];
            __builtin_amdgcn_global_load_lds((gvoid*)gp, (lvoid*)lp, 16, 0, 0);
        }
    };
    auto compute = [&](int slot) {
#pragma unroll
        for (int ks = 0; ks < 2; ++ks) {
            bf16x8 af[2], bfr[2];
#pragma unroll
            for (int m = 0; m < 2; ++m) {
                int r = wm * 32 + m * 16 + lane15;
                int c = ks * 4 + lane4;
                af[m] = *(const bf16x8*)&As[slot][((r << 3) | (c ^ (r & 7))) << 3];
            }
#pragma unroll
            for (int n = 0; n < 2; ++n) {
                int rn = wn * 32 + n * 16 + lane15;
                int c = ks * 4 + lane4;
                bfr[n] = *(const bf16x8*)&Bs[slot][((rn << 3) | (c ^ (rn & 7))) << 3];
            }
#pragma unroll
            for (int m = 0; m < 2; ++m)
#pragma unroll
                for (int n = 0; n < 2; ++n)
                    acc[m][n] = __builtin_amdgcn_mfma_f32_16x16x32_bf16(
                        af[m], bfr[n], acc[m][n], 0, 0, 0);
        }
    };

    // prologue: tile 0
    loadA(kbase);                                   // 4 vm
    stageB(0, kbase);                               // 2 vm
    asm volatile("s_waitcnt vmcnt(2)" ::: "memory");   // A regs ready (B(0) may fly)
    writeA(0, kbase);                               // ds_write + 2 stores
    asm volatile("s_waitcnt lgkmcnt(0)" ::: "memory"); // publish ds_writes

    const int NIT = 16;
    for (int tt = 0; tt < NIT; ++tt) {
        if (tt + 1 < NIT) {
            const int kt1 = kbase + (tt + 1) * 64;
            loadA(kt1);                             // 4 vm
            stageB((tt + 1) & 1, kt1);              // 2 vm
            // retire tile-t's B-glds: ops after them = st(t)2 + A(t+1)4 + B(t+1)2
            asm volatile("s_waitcnt vmcnt(8)\n\ts_barrier" ::: "memory");
        } else {
            asm volatile("s_waitcnt vmcnt(0)\n\ts_barrier" ::: "memory");
        }
        compute(tt & 1);
        if (tt + 1 < NIT) {
            // retire A(t+1) regs: only B(t+1)'s 2 glds may remain in flight
            asm volatile("s_waitcnt vmcnt(2)" ::: "memory");
            writeA((tt + 1) & 1, kbase + (tt + 1) * 64);   // ds_write + stores
            asm volatile("s_waitcnt lgkmcnt(0)" ::: "memory");
        }
        asm volatile("s_barrier" ::: "memory");     // compute(t) done + As published
    }

    // C/D layout: col = lane&15, row = (lane>>4)*4 + q
    float* Po = P + (size_t)blockIdx.y * (8192 * 64);
#pragma unroll
    for (int m = 0; m < 2; ++m) {
        int r = row0 + wm * 32 + m * 16 + lane4 * 4;
#pragma unroll
        for (int n = 0; n < 2; ++n) {
            int cc = wn * 32 + n * 16 + lane15;
#pragma unroll
            for (int q = 0; q < 4; ++q)
                Po[(size_t)(r + q) * 64 + cc] = acc[m][n][q];
        }
    }
}

// ---------------- big GEMM (R5 verbatim): P[ks] = Abf @ Y ----------------
__global__ __launch_bounds__(256, 4)
void big_gemm(const unsigned short* __restrict__ Ab,
              const unsigned short* __restrict__ Yt,
              float* __restrict__ P) {
    __shared__ unsigned short As[2][64 * 64];
    __shared__ unsigned short Bs[2][64 * 64];
    const int t = threadIdx.x;
    const int lane = t & 63, wid = t >> 6;
    const int lane15 = lane & 15, lane4 = lane >> 4;
    const int wm = wid >> 1, wn = wid & 1;
    const int row0 = blockIdx.x * 64;
    const int kbase = blockIdx.y * 1024;

    f32x4 acc[2][2];
    const f32x4 z4 = {0.f, 0.f, 0.f, 0.f};
#pragma unroll
    for (int m = 0; m < 2; ++m)
#pragma unroll
        for (int n = 0; n < 2; ++n) acc[m][n] = z4;

    auto stage = [&](int slot, int kt) {
#pragma unroll
        for (int ii = 0; ii < 2; ++ii) {
            int p = ii * 256 + wid * 64 + lane;
            int r = p >> 3;
            int c = (p & 7) ^ (r & 7);
            const unsigned short* gp = Ab + (size_t)(row0 + r) * 8192 + (kt + c * 8);
            unsigned short* lp = &As[slot][(ii * 256 + wid * 64) * 8];
            __builtin_amdgcn_global_load_lds((gvoid*)gp, (lvoid*)lp, 16, 0, 0);
        }
#pragma unroll
        for (int ii = 0; ii < 2; ++ii) {
            int q = ii * 256 + wid * 64 + lane;
            int n = q >> 3;
            int c = (q & 7) ^ (n & 7);
            const unsigned short* gp = Yt + (size_t)n * 8192 + (kt + c * 8);
            unsigned short* lp = &Bs[slot][(ii * 256 + wid * 64) * 8];
            __builtin_amdgcn_global_load_lds((gvoid*)gp, (lvoid*)lp, 16, 0, 0);
        }
    };

    stage(0, kbase);
    const int NIT = 16;
    for (int tt = 0; tt < NIT; ++tt) {
        if (tt + 1 < NIT) {
            stage((tt + 1) & 1, kbase + (tt + 1) * 64);
            asm volatile("s_waitcnt vmcnt(4)\n\ts_barrier" ::: "memory");
        } else {
            asm volatile("s_waitcnt vmcnt(0)\n\ts_barrier" ::: "memory");
        }
#pragma unroll
        for (int ks = 0; ks < 2; ++ks) {
            bf16x8 af[2], bfr[2];
#pragma unroll
            for (int m = 0; m < 2; ++m) {
                int r = wm * 32 + m * 16 + lane15;
                int c = ks * 4 + lane4;
                af[m] = *(const bf16x8*)&As[tt & 1][((r << 3) | (c ^ (r & 7))) << 3];
            }
#pragma unroll
            for (int n = 0; n < 2; ++n) {
                int rn = wn * 32 + n * 16 + lane15;
                int c = ks * 4 + lane4;
                bfr[n] = *(const bf16x8*)&Bs[tt & 1][((rn << 3) | (c ^ (rn & 7))) << 3];
            }
#pragma unroll
            for (int m = 0; m < 2; ++m)
#pragma unroll
                for (int n = 0; n < 2; ++n)
                    acc[m][n] = __builtin_amdgcn_mfma_f32_16x16x32_bf16(
                        af[m], bfr[n], acc[m][n], 0, 0, 0);
        }
        asm volatile("s_barrier" ::: "memory");
    }

    float* Po = P + (size_t)blockIdx.y * (8192 * 64);
#pragma unroll
    for (int m = 0; m < 2; ++m) {
        int r = row0 + wm * 32 + m * 16 + lane4 * 4;
#pragma unroll
        for (int n = 0; n < 2; ++n) {
            int cc = wn * 32 + n * 16 + lane15;
#pragma unroll
            for (int q = 0; q < 4; ++q)
                Po[(size_t)(r + q) * 64 + cc] = acc[m][n][q];
        }
    }
}

// ---------------- fused: reduce split-K(8) + poly + next layer's small GEMM --------
template <int MODE>
__global__ __launch_bounds__(256) void fused_reduce(const float* __restrict__ P,
                                                    const float* __restrict__ cf,
                                                    const float* __restrict__ Wn,
                                                    const float* __restrict__ bn,
                                                    int cout,
                                                    float* __restrict__ X1,
                                                    unsigned short* __restrict__ Yt) {
    __shared__ float Xs[64 * 33];   // [j][i]
    __shared__ float Ws[64 * 64];
    __shared__ float bs[64];
    const int t = threadIdx.x;
    const int i0 = blockIdx.x * 32;
    const int NT4 = 8192 * 64 / 4;
    const float4* P4 = (const float4*)P;
    float4* X14 = (float4*)X1;

    for (int e = t; e < 64 * 64; e += 256) {
        int k = e >> 6, j = e & 63;
        Ws[e] = (j < cout) ? Wn[k * cout + j] : 0.0f;
    }
    if (t < 64) bs[t] = (t < cout) ? bn[t] : 0.0f;
    const float c0 = cf[0], c1 = cf[1], c2 = cf[2];

#pragma unroll
    for (int s = 0; s < 2; ++s) {
        int e4 = s * 256 + t;
        int i = e4 >> 4, jc = e4 & 15;
        int base4 = (i0 + i) * 16 + jc;
        float4 z = {0.f, 0.f, 0.f, 0.f};
#pragma unroll
        for (int ks = 0; ks < 8; ++ks) {
            float4 p = P4[(size_t)ks * NT4 + base4];
            z.x += p.x; z.y += p.y; z.z += p.z; z.w += p.w;
        }
        float4 v;
        v.x = z.x * (c0 + z.x * (c1 + z.x * c2));
        v.y = z.y * (c0 + z.y * (c1 + z.y * c2));
        v.z = z.z * (c0 + z.z * (c1 + z.z * c2));
        v.w = z.w * (c0 + z.w * (c1 + z.w * c2));
        if (MODE == 0) {
            X14[base4] = v;
        } else {
            float4 xr = X14[base4];
            v.x += xr.x; v.y += xr.y; v.z += xr.z; v.w += xr.w;
        }
        Xs[(jc * 4 + 0) * 33 + i] = v.x;
        Xs[(jc * 4 + 1) * 33 + i] = v.y;
        Xs[(jc * 4 + 2) * 33 + i] = v.z;
        Xs[(jc * 4 + 3) * 33 + i] = v.w;
    }
    __syncthreads();

    const int i = t & 31;
    const int jg = t >> 5;
    float acc[8];
#pragma unroll
    for (int jj = 0; jj < 8; ++jj) acc[jj] = 0.0f;
    for (int k = 0; k < 64; ++k) {
        float xv = Xs[k * 33 + i];
        const float4* wr = (const float4*)&Ws[k * 64 + jg * 8];
        float4 w0 = wr[0], w1 = wr[1];
        acc[0] += xv * w0.x; acc[1] += xv * w0.y;
        acc[2] += xv * w0.z; acc[3] += xv * w0.w;
        acc[4] += xv * w1.x; acc[5] += xv * w1.y;
        acc[6] += xv * w1.z; acc[7] += xv * w1.w;
    }
#pragma unroll
    for (int jj = 0; jj < 8; ++jj) {
        int j = jg * 8 + jj;
        Yt[(size_t)j * 8192 + i0 + i] = f2bf(acc[jj] + bs[j]);
    }
}

// ---------------- final: reduce(8) + poly -> out [8192 x 40], float4 ----------------
__global__ void reduce_out(const float* __restrict__ P, const float* __restrict__ cf,
                           float* __restrict__ out) {
    int e4 = blockIdx.x * 256 + threadIdx.x;
    const int NT4 = 8192 * 64 / 4;
    const float4* P4 = (const float4*)P;
    float4 z = {0.f, 0.f, 0.f, 0.f};
#pragma unroll
    for (int ks = 0; ks < 8; ++ks) {
        float4 p = P4[(size_t)ks * NT4 + e4];
        z.x += p.x; z.y += p.y; z.z += p.z; z.w += p.w;
    }
    float c0 = cf[0], c1 = cf[1], c2 = cf[2];
    float4 v;
    v.x = z.x * (c0 + z.x * (c1 + z.x * c2));
    v.y = z.y * (c0 + z.y * (c1 + z.y * c2));
    v.z = z.z * (c0 + z.z * (c1 + z.z * c2));
    v.w = z.w * (c0 + z.w * (c1 + z.w * c2));
    int i = e4 >> 4, jc = e4 & 15;
    if (jc < 10) ((float4*)out)[i * 10 + jc] = v;
}

extern "C" void kernel_launch(void* const* d_in, const int* in_sizes, int n_in,
                              void* d_out, int out_size, void* d_ws, size_t ws_size,
                              hipStream_t stream) {
    const float* nf   = (const float*)d_in[0];
    const float* Amat = (const float*)d_in[1];
    const float* W1   = (const float*)d_in[2];
    const float* b1   = (const float*)d_in[3];
    const float* c1   = (const float*)d_in[4];
    const float* W2   = (const float*)d_in[5];
    const float* b2   = (const float*)d_in[6];
    const float* c2   = (const float*)d_in[7];
    const float* W3   = (const float*)d_in[8];
    const float* b3   = (const float*)d_in[9];
    const float* c3   = (const float*)d_in[10];
    float* out = (float*)d_out;

    char* ws = (char*)d_ws;
    unsigned short* Abf = (unsigned short*)(ws);                 // 134217728 B
    unsigned short* Yt  = (unsigned short*)(ws + 134217728);     //   1048576 B
    float* X1           = (float*)(ws + 135266304);              //   2097152 B
    float* Pp           = (float*)(ws + 137363456);              //  16777216 B
    // total: 154140672 B

    // layer-1 feature transform
    small_gemm<128><<<256, 256, 0, stream>>>(nf, W1, b1, 64, Yt);

    // layer 1 GEMM with fused fp32->bf16 conversion (writes Abf for layers 2/3)
    gemm_conv<<<dim3(128, 8), 256, 0, stream>>>(Amat, Abf, Yt, Pp);
    fused_reduce<0><<<256, 256, 0, stream>>>(Pp, c1, W2, b2, 64, X1, Yt);

    // layer 2 (residual folded into fused_reduce<1>)
    big_gemm<<<dim3(128, 8), 256, 0, stream>>>(Abf, Yt, Pp);
    fused_reduce<1><<<256, 256, 0, stream>>>(Pp, c2, W3, b3, 40, X1, Yt);

    // layer 3
    big_gemm<<<dim3(128, 8), 256, 0, stream>>>(Abf, Yt, Pp);
    reduce_out<<<512, 256, 0, stream>>>(Pp, c3, out);
}